// Round 25
// baseline (921.781 us; speedup 1.0000x reference)
//
#include <hip/hip_runtime.h>
#include <hip/hip_bf16.h>
#include <math.h>

#define NB 16
#define TT 4096
#define LL 512
#define DM 128
#define DI 256
#define NLAYER 6
#define CL 32
#define NCH 16

typedef __bf16 bf16x8 __attribute__((ext_vector_type(8)));
typedef float f32x4 __attribute__((ext_vector_type(4)));
typedef unsigned short ushort;

static __device__ __forceinline__ float gelu_f(float v){
  return 0.5f*v*(1.f + erff(v*0.70710678118654752f));
}
static __device__ __forceinline__ float silu_f(float v){
  return v/(1.f + __expf(-v));
}
static __device__ __forceinline__ ushort f2b(float v){
  __hip_bfloat16 h = __float2bfloat16(v);
  return *(ushort*)&h;
}

__global__ __launch_bounds__(256) void k_maskmul(const float* __restrict__ x, const float* __restrict__ m,
                          float* __restrict__ out, int n){
  int i = blockIdx.x*256 + threadIdx.x;
  if (i < n) out[i] = x[i]*m[i];
}

__global__ __launch_bounds__(256) void k_castb(const float* __restrict__ in, ushort* __restrict__ out, int n){
  int i = blockIdx.x*256 + threadIdx.x;
  if (i < n) out[i] = f2b(in[i]);
}

// transpose weights (Ci,Co,3) -> (Co,Ci,3)
__global__ __launch_bounds__(256) void k_trw(const float* __restrict__ in, float* __restrict__ out, int Ci, int Co){
  int idx = blockIdx.x*256 + threadIdx.x;
  int n = Ci*Co*3;
  if (idx >= n) return;
  int k = idx % 3;
  int o = (idx/3) % Co;
  int ci = idx/(3*Co);
  out[((size_t)o*Ci + ci)*3 + k] = in[idx];
}

// LDS-staged conv1d stride2 pad1 k3. block=(b, L-chunk, Co-split). W (Co,Ci,3).
template<int Ci, int Co, int TW, int OS>
__global__ __launch_bounds__(256) void k_conv_lds(const float* __restrict__ x, const float* __restrict__ W,
                        const float* __restrict__ bias, float* __restrict__ y, int Li){
  const int Lc = TW;
  const int Lo = Li >> 1;
  const int S  = Lo / Lc;
  const int CoB = Co / OS;
  __shared__ float xe[Ci][Lc+1];
  __shared__ float xo[Ci][Lc+1];
  int bid = blockIdx.x;
  int os = bid % OS;
  int ch = (bid / OS) % S;
  int b  = bid / (OS*S);
  int t0 = ch*Lc;
  const float* xb = x + (size_t)b*Ci*Li;
  for (int idx = threadIdx.x; idx < Ci*(2*Lc+1); idx += 256){
    int ci = idx / (2*Lc+1);
    int j  = idx - ci*(2*Lc+1);
    int gin = 2*t0 - 1 + j;
    float v = (gin >= 0 && gin < Li) ? xb[(size_t)ci*Li + gin] : 0.f;
    if (j & 1) xo[ci][j>>1] = v;
    else       xe[ci][j>>1] = v;
  }
  __syncthreads();
  const int NOg = 256/TW;
  const int OI  = CoB/NOg;
  int tl = threadIdx.x % TW;
  int og = threadIdx.x / TW;
  #pragma unroll
  for (int oi = 0; oi < OI; oi++){
    int o = os*CoB + oi*NOg + og;
    const float* w = W + (size_t)o*Ci*3;
    float acc = bias[o];
    #pragma unroll 4
    for (int ci = 0; ci < Ci; ci++){
      float w0 = w[ci*3+0], w1 = w[ci*3+1], w2 = w[ci*3+2];
      acc += w0*xe[ci][tl] + w1*xo[ci][tl] + w2*xe[ci][tl+1];
    }
    y[((size_t)b*Co + o)*Lo + t0 + tl] = acc;
  }
}

// -------- GroupNorm(1): wide 2-kernel version --------
__global__ __launch_bounds__(256) void k_gn_part(const float* __restrict__ x, float* __restrict__ gp){
  int b = blockIdx.x >> 3, k8 = blockIdx.x & 7;
  const float* xb = x + (size_t)b*65536 + (size_t)k8*8192;
  float s = 0.f, s2 = 0.f;
  for (int i = threadIdx.x; i < 8192; i += 256){ float v = xb[i]; s += v; s2 += v*v; }
  #pragma unroll
  for (int o = 32; o; o >>= 1){ s += __shfl_down(s, o); s2 += __shfl_down(s2, o); }
  __shared__ float sh[8];
  int wid = threadIdx.x >> 6;
  if ((threadIdx.x & 63) == 0){ sh[wid] = s; sh[wid+4] = s2; }
  __syncthreads();
  if (threadIdx.x == 0){
    float a = sh[0]+sh[1]+sh[2]+sh[3], a2 = sh[4]+sh[5]+sh[6]+sh[7];
    gp[(b*8+k8)*2+0] = a; gp[(b*8+k8)*2+1] = a2;
  }
}
__global__ __launch_bounds__(256) void k_gn_apply(float* __restrict__ x, const float* __restrict__ g,
                          const float* __restrict__ be, int Tl, const float* __restrict__ gp){
  int gidx = blockIdx.x*256 + threadIdx.x;
  int b = gidx >> 16, i = gidx & 65535;
  float s = 0.f, s2 = 0.f;
  #pragma unroll
  for (int k = 0; k < 8; k++){ s += gp[(b*8+k)*2]; s2 += gp[(b*8+k)*2+1]; }
  float mean = s*(1.f/65536.f);
  float inv  = rsqrtf(s2*(1.f/65536.f) - mean*mean + 1e-5f);
  int c = i / Tl;
  float* p = x + (size_t)b*65536 + i;
  float v = (*p - mean)*inv*g[c] + be[c];
  *p = gelu_f(v);
}

// (B,128,512) NCH -> (B,512,128) BLD.
__global__ __launch_bounds__(256) void k_transpose2(const float* __restrict__ in, float* __restrict__ out){
  int idx = blockIdx.x*256 + threadIdx.x;
  if (idx >= NB*DM*LL) return;
  int t = idx & 511;
  int c = (idx >> 9) & 127;
  int b = idx >> 16;
  out[(size_t)b*65536 + (size_t)t*128 + c] = in[idx];
}

// (B,512,128) BLD -> (B,128,512) NCH.
__global__ __launch_bounds__(256) void k_transposeB(const float* __restrict__ in, float* __restrict__ out){
  int idx = blockIdx.x*256 + threadIdx.x;
  if (idx >= NB*DM*LL) return;
  int m = idx & 511;
  int c = (idx >> 9) & 127;
  int b = idx >> 16;
  out[idx] = in[(size_t)b*65536 + (size_t)m*128 + c];
}

// LayerNorm last-dim(128) -> f32 out.
__global__ __launch_bounds__(256) void k_ln2(const float* __restrict__ x, const float* __restrict__ g,
                      const float* __restrict__ be, float* __restrict__ out, int rows){
  int row = blockIdx.x*4 + (threadIdx.x >> 6);
  if (row >= rows) return;
  int lid = threadIdx.x & 63;
  const float* xr = x + (size_t)row*DM;
  float v0 = xr[lid], v1 = xr[lid+64];
  float s = v0 + v1;
  #pragma unroll
  for (int o = 32; o; o >>= 1) s += __shfl_xor(s, o);
  float mean = s*(1.f/128.f);
  float d0 = v0-mean, d1 = v1-mean;
  float s2 = d0*d0 + d1*d1;
  #pragma unroll
  for (int o = 32; o; o >>= 1) s2 += __shfl_xor(s2, o);
  float inv = rsqrtf(s2*(1.f/128.f) + 1e-5f);
  float* orow = out + (size_t)row*DM;
  orow[lid]    = d0*inv*g[lid]    + be[lid];
  orow[lid+64] = d1*inv*g[lid+64] + be[lid+64];
}

// LayerNorm -> bf16 out.
__global__ __launch_bounds__(256) void k_ln2b(const float* __restrict__ x, const float* __restrict__ g,
                      const float* __restrict__ be, ushort* __restrict__ out, int rows){
  int row = blockIdx.x*4 + (threadIdx.x >> 6);
  if (row >= rows) return;
  int lid = threadIdx.x & 63;
  const float* xr = x + (size_t)row*DM;
  float v0 = xr[lid], v1 = xr[lid+64];
  float s = v0 + v1;
  #pragma unroll
  for (int o = 32; o; o >>= 1) s += __shfl_xor(s, o);
  float mean = s*(1.f/128.f);
  float d0 = v0-mean, d1 = v1-mean;
  float s2 = d0*d0 + d1*d1;
  #pragma unroll
  for (int o = 32; o; o >>= 1) s2 += __shfl_xor(s2, o);
  float inv = rsqrtf(s2*(1.f/128.f) + 1e-5f);
  ushort* orow = out + (size_t)row*DM;
  orow[lid]    = f2b(d0*inv*g[lid]    + be[lid]);
  orow[lid+64] = f2b(d1*inv*g[lid+64] + be[lid+64]);
}

// bf16 MFMA GEMM with SPLIT epilogue: cols<256 -> C0 (xi), cols>=256 -> C1 (z).
__global__ __launch_bounds__(256) void k_mfma_split(const ushort* __restrict__ A, const ushort* __restrict__ B,
                          float* __restrict__ C0, float* __restrict__ C1, int K){
  int tid = threadIdx.x;
  int wid = tid >> 6, l = tid & 63;
  int wm = wid >> 1, wn = wid & 1;
  int m0 = blockIdx.y*128 + wm*64;
  int n0 = blockIdx.x*128 + wn*64;
  int lr = l & 15;
  int lk = (l >> 4)*8;
  int orow = (l >> 4)*4;
  f32x4 acc[4][4];
  #pragma unroll
  for (int i = 0; i < 4; i++)
    #pragma unroll
    for (int j = 0; j < 4; j++) acc[i][j] = (f32x4){0.f,0.f,0.f,0.f};
  for (int k0 = 0; k0 < K; k0 += 32){
    bf16x8 a[4], b[4];
    #pragma unroll
    for (int f = 0; f < 4; f++)
      a[f] = *(const bf16x8*)(A + (size_t)(m0 + f*16 + lr)*K + k0 + lk);
    #pragma unroll
    for (int f = 0; f < 4; f++)
      b[f] = *(const bf16x8*)(B + (size_t)(n0 + f*16 + lr)*K + k0 + lk);
    #pragma unroll
    for (int i = 0; i < 4; i++)
      #pragma unroll
      for (int j = 0; j < 4; j++)
        acc[i][j] = __builtin_amdgcn_mfma_f32_16x16x32_bf16(a[i], b[j], acc[i][j], 0, 0, 0);
  }
  float* C    = (n0 < 256) ? C0 : C1;
  int ncol0   = (n0 < 256) ? n0 : n0 - 256;
  #pragma unroll
  for (int i = 0; i < 4; i++)
    #pragma unroll
    for (int j = 0; j < 4; j++)
      #pragma unroll
      for (int r = 0; r < 4; r++)
        C[(size_t)(m0 + i*16 + orow + r)*256 + ncol0 + j*16 + lr] = acc[i][j][r];
}

// bf16 MFMA out-proj (accumulate), 32x128 block tile, wave = 32x32. grid = M/32 = 256 blocks.
__global__ __launch_bounds__(256) void k_mfma_acc2(const ushort* __restrict__ A, const ushort* __restrict__ B,
                          float* __restrict__ C, int K){
  int tid = threadIdx.x;
  int wid = tid >> 6, l = tid & 63;
  int m0 = blockIdx.x*32;
  int n0 = wid*32;
  int lr = l & 15;
  int lk = (l >> 4)*8;
  int orow = (l >> 4)*4;
  f32x4 acc[2][2];
  #pragma unroll
  for (int i = 0; i < 2; i++)
    #pragma unroll
    for (int j = 0; j < 2; j++)
      #pragma unroll
      for (int r = 0; r < 4; r++)
        acc[i][j][r] = C[(size_t)(m0 + i*16 + orow + r)*128 + n0 + j*16 + lr];
  for (int k0 = 0; k0 < K; k0 += 32){
    bf16x8 a[2], b[2];
    #pragma unroll
    for (int f = 0; f < 2; f++)
      a[f] = *(const bf16x8*)(A + (size_t)(m0 + f*16 + lr)*K + k0 + lk);
    #pragma unroll
    for (int f = 0; f < 2; f++)
      b[f] = *(const bf16x8*)(B + (size_t)(n0 + f*16 + lr)*K + k0 + lk);
    #pragma unroll
    for (int i = 0; i < 2; i++)
      #pragma unroll
      for (int j = 0; j < 2; j++)
        acc[i][j] = __builtin_amdgcn_mfma_f32_16x16x32_bf16(a[i], b[j], acc[i][j], 0, 0, 0);
  }
  #pragma unroll
  for (int i = 0; i < 2; i++)
    #pragma unroll
    for (int j = 0; j < 2; j++)
      #pragma unroll
      for (int r = 0; r < 4; r++)
        C[(size_t)(m0 + i*16 + orow + r)*128 + n0 + j*16 + lr] = acc[i][j][r];
}

// xp-proj GEMM f32: 32x64 tile (N=40 guarded).
__global__ __launch_bounds__(256) void k_gemm_xp(const float* __restrict__ A, const float* __restrict__ B,
                          float* __restrict__ C){
  __shared__ float As[32][17];
  __shared__ float Bs[64][17];
  int tid = threadIdx.x;
  int m0 = blockIdx.x*32;
  int tx = tid & 15, ty = tid >> 4;
  float acc[2][4] = {};
  for (int k0 = 0; k0 < 256; k0 += 16){
    if (tid < 128){
      int r = tid >> 2, c = (tid & 3)*4;
      float4 av = *(const float4*)(A + (size_t)(m0+r)*256 + k0 + c);
      As[r][c]=av.x; As[r][c+1]=av.y; As[r][c+2]=av.z; As[r][c+3]=av.w;
    }
    {
      int r = tid >> 2, c = (tid & 3)*4;
      float4 bv = make_float4(0.f,0.f,0.f,0.f);
      if (r < 40) bv = *(const float4*)(B + (size_t)r*256 + k0 + c);
      Bs[r][c]=bv.x; Bs[r][c+1]=bv.y; Bs[r][c+2]=bv.z; Bs[r][c+3]=bv.w;
    }
    __syncthreads();
    #pragma unroll
    for (int k = 0; k < 16; k++){
      float a[2], bb[4];
      #pragma unroll
      for (int i = 0; i < 2; i++) a[i] = As[ty*2+i][k];
      #pragma unroll
      for (int j = 0; j < 4; j++) bb[j] = Bs[tx*4+j][k];
      #pragma unroll
      for (int i = 0; i < 2; i++)
        #pragma unroll
        for (int j = 0; j < 4; j++) acc[i][j] += a[i]*bb[j];
    }
    __syncthreads();
  }
  #pragma unroll
  for (int i = 0; i < 2; i++){
    int m = m0 + ty*2 + i;
    #pragma unroll
    for (int j = 0; j < 4; j++){
      int n = tx*4 + j;
      if (n < 40) C[(size_t)m*40 + n] = acc[i][j];
    }
  }
}

// depthwise causal conv k=4 over dense XI (B,L,256), +bias, SiLU -> XC (B,L,256)
__global__ __launch_bounds__(256) void k_cconv2(const float* __restrict__ xi, const float* __restrict__ cw,
                         const float* __restrict__ cb, float* __restrict__ xc){
  int idx = blockIdx.x*256 + threadIdx.x;
  if (idx >= NB*LL*DI) return;
  int d = idx & 255;
  int l = (idx >> 8) & 511;
  int b = idx >> 17;
  const float* xp = xi + (size_t)b*131072 + d;
  float acc = cb[d];
  #pragma unroll
  for (int j = 0; j < 4; j++){
    int m = l - 3 + j;
    if (m >= 0) acc += xp[(size_t)m*256]*cw[d*4 + j];
  }
  xc[idx] = silu_f(acc);
}

// ---------------- chunked scan, thread = d ----------------
__global__ __launch_bounds__(256) void k_scan_sum(const float* __restrict__ xc, const float* __restrict__ dbl,
                        const float* __restrict__ dtW, const float* __restrict__ dtb,
                        const float* __restrict__ Alog,
                        float* __restrict__ GA, float* __restrict__ GB){
  __shared__ float srow[CL*40];
  int bid = blockIdx.x;
  int b = bid >> 4, ch = bid & 15;
  int d = threadIdx.x;
  const float* dbp = dbl + (size_t)b*20480 + ch*CL*40;
  for (int j = d; j < CL*40; j += 256) srow[j] = dbp[j];
  float4 w0 = *(const float4*)(dtW + d*8);
  float4 w1 = *(const float4*)(dtW + d*8 + 4);
  float tb = dtb[d];
  float a[16];
  #pragma unroll
  for (int s = 0; s < 16; s++) a[s] = -__expf(Alog[d*16 + s]);
  const float* xcp = xc + (size_t)b*131072 + (size_t)ch*CL*256 + d;
  __syncthreads();
  float A[16], Bv[16];
  #pragma unroll
  for (int s = 0; s < 16; s++){ A[s] = 1.f; Bv[s] = 0.f; }
  #pragma unroll 2
  for (int i = 0; i < CL; i++){
    const float* r = srow + i*40;
    float raw = tb + r[0]*w0.x + r[1]*w0.y + r[2]*w0.z + r[3]*w0.w
                   + r[4]*w1.x + r[5]*w1.y + r[6]*w1.z + r[7]*w1.w;
    float dt = (raw > 20.f) ? raw : log1pf(__expf(raw));
    float xcv = xcp[(size_t)i*256];
    float dxc = dt*xcv;
    #pragma unroll
    for (int s = 0; s < 16; s++){
      float e = __expf(dt*a[s]);
      A[s] *= e;
      Bv[s] = e*Bv[s] + dxc*r[8+s];
    }
  }
  size_t base = (((size_t)b*NCH + ch)*16)*256 + d;
  #pragma unroll
  for (int s = 0; s < 16; s++){
    GA[base + (size_t)s*256] = A[s];
    GB[base + (size_t)s*256] = Bv[s];
  }
}

// replay + gate with INLINE chunk prefix (reads raw GA/GB chunk sums; scan_pre folded in).
__global__ __launch_bounds__(256) void k_scan_emit(const float* __restrict__ xc, const float* __restrict__ dbl,
                        const float* __restrict__ z,
                        const float* __restrict__ dtW, const float* __restrict__ dtb,
                        const float* __restrict__ Alog, const float* __restrict__ Dp,
                        const float* __restrict__ GA, const float* __restrict__ GBr,
                        ushort* __restrict__ yb){
  __shared__ float srow[CL*40];
  int bid = blockIdx.x;
  int b = bid >> 4, ch = bid & 15;
  int d = threadIdx.x;
  const float* dbp = dbl + (size_t)b*20480 + ch*CL*40;
  for (int j = d; j < CL*40; j += 256) srow[j] = dbp[j];
  float4 w0 = *(const float4*)(dtW + d*8);
  float4 w1 = *(const float4*)(dtW + d*8 + 4);
  float tb = dtb[d];
  float Dd = Dp[d];
  float a[16];
  #pragma unroll
  for (int s = 0; s < 16; s++) a[s] = -__expf(Alog[d*16 + s]);
  // inline exclusive prefix over chunks < ch (same combine order as k_scan_pre)
  float h[16];
  #pragma unroll
  for (int s = 0; s < 16; s++) h[s] = 0.f;
  {
    size_t cstride = (size_t)16*256;
    size_t bb = (((size_t)b*NCH)*16)*256 + d;
    for (int cc = 0; cc < ch; cc++){
      #pragma unroll
      for (int s = 0; s < 16; s++){
        float Ac = GA[bb + (size_t)s*256];
        float Bc = GBr[bb + (size_t)s*256];
        h[s] = Ac*h[s] + Bc;
      }
      bb += cstride;
    }
  }
  const float* xcp = xc + (size_t)b*131072 + (size_t)ch*CL*256 + d;
  const float* zp  = z  + (size_t)b*131072 + (size_t)ch*CL*256 + d;
  ushort* yp = yb + (size_t)b*131072 + (size_t)ch*CL*256 + d;
  __syncthreads();
  #pragma unroll 2
  for (int i = 0; i < CL; i++){
    const float* r = srow + i*40;
    float raw = tb + r[0]*w0.x + r[1]*w0.y + r[2]*w0.z + r[3]*w0.w
                   + r[4]*w1.x + r[5]*w1.y + r[6]*w1.z + r[7]*w1.w;
    float dt = (raw > 20.f) ? raw : log1pf(__expf(raw));
    float xcv = xcp[(size_t)i*256];
    float dxc = dt*xcv;
    float y = Dd*xcv;
    #pragma unroll
    for (int s = 0; s < 16; s++){
      float e = __expf(dt*a[s]);
      h[s] = e*h[s] + dxc*r[8+s];
      y += h[s]*r[24+s];
    }
    float zv = zp[(size_t)i*256];
    yp[(size_t)i*256] = f2b(y*silu_f(zv));
  }
}

// LDS-staged paired deconv, transposed weights (Co,Ci,3), Co-split OS.
template<int Ci, int Co, int TW, int OS>
__global__ __launch_bounds__(256) void k_deconv_lds(const float* __restrict__ x, const float* __restrict__ WT,
                          const float* __restrict__ bias, float* __restrict__ y, int Li, int cs){
  const int Lc = TW;
  const int S  = Li / Lc;
  const int CoB = Co / OS;
  __shared__ float xin[Ci][Lc+1];
  int bid = blockIdx.x;
  int os = bid % OS;
  int ch = (bid / OS) % S;
  int b  = bid / (OS*S);
  int m0 = ch*Lc;
  const float* xb = x + (size_t)b*Ci*Li;
  for (int idx = threadIdx.x; idx < Ci*(Lc+1); idx += 256){
    int ci = idx / (Lc+1);
    int q  = idx - ci*(Lc+1);
    int m  = m0 + q;
    xin[ci][q] = (m < Li) ? xb[(size_t)ci*cs + m] : 0.f;
  }
  __syncthreads();
  const int NOg = 256/TW;
  const int OI  = CoB/NOg;
  int tl = threadIdx.x % TW;
  int og = threadIdx.x / TW;
  float* yo = y + (size_t)b*Co*(size_t)(2*Li);
  #pragma unroll
  for (int oi = 0; oi < OI; oi++){
    int o = os*CoB + oi*NOg + og;
    const float* w = WT + (size_t)o*Ci*3;
    float bo = bias[o];
    float even = bo, odd = bo;
    #pragma unroll 4
    for (int ci = 0; ci < Ci; ci++){
      float w0 = w[ci*3+0], w1 = w[ci*3+1], w2 = w[ci*3+2];
      float xm  = xin[ci][tl];
      float xm1 = xin[ci][tl+1];
      even += w1*xm;
      odd  += w2*xm + w0*xm1;
    }
    *(float2*)(yo + (size_t)o*(2*Li) + 2*(m0 + tl)) = make_float2(even, odd);
  }
}

// paired deconv (non-LDS) for dec2 (Co=2).
__global__ __launch_bounds__(256) void k_deconv2p(const float* __restrict__ x, const float* __restrict__ W,
                          const float* __restrict__ bias, float* __restrict__ y,
                          int Ci, int Co, int Li, int cs, int S){
  __shared__ float w[384];
  int bid = blockIdx.x;
  int ch = bid % S;
  int o  = (bid / S) % Co;
  int b  = bid / (S*Co);
  for (int j = threadIdx.x; j < Ci*3; j += 256){
    int i = j/3, k = j - 3*i;
    w[j] = W[((size_t)i*Co + o)*3 + k];
  }
  __syncthreads();
  int Lc = Li / S;
  int m0 = ch*Lc;
  const float* xb = x + (size_t)b*Ci*Li;
  float bo = bias[o];
  float* yo = y + ((size_t)b*Co + o)*(size_t)(2*Li);
  for (int idx = threadIdx.x; idx < Lc; idx += 256){
    int m = m0 + idx;
    float even = bo, odd = bo;
    bool has1 = (m + 1 < Li);
    for (int i = 0; i < Ci; i++){
      const float* xr = xb + (size_t)i*cs;
      float xm  = xr[m];
      float xm1 = has1 ? xr[m+1] : 0.f;
      even += w[i*3+1]*xm;
      odd  += w[i*3+2]*xm + w[i*3+0]*xm1;
    }
    *(float2*)(yo + 2*m) = make_float2(even, odd);
  }
}

__global__ __launch_bounds__(256) void k_copyf(const float* __restrict__ in, float* __restrict__ out, int n){
  int i = blockIdx.x*256 + threadIdx.x;
  if (i < n) out[i] = in[i];
}

extern "C" void kernel_launch(void* const* d_in, const int* in_sizes, int n_in,
                              void* d_out, int out_size, void* d_ws, size_t ws_size,
                              hipStream_t stream) {
  const float* x      = (const float*)d_in[0];
  const float* mask   = (const float*)d_in[1];
  const float* enc_W0 = (const float*)d_in[2];
  const float* enc_b0 = (const float*)d_in[3];
  const float* enc_g0 = (const float*)d_in[4];
  const float* enc_be0= (const float*)d_in[5];
  const float* enc_W1 = (const float*)d_in[6];
  const float* enc_b1 = (const float*)d_in[7];
  const float* enc_g1 = (const float*)d_in[8];
  const float* enc_be1= (const float*)d_in[9];
  const float* enc_W2 = (const float*)d_in[10];
  const float* enc_b2 = (const float*)d_in[11];
  const float* enc_g2 = (const float*)d_in[12];
  const float* enc_be2= (const float*)d_in[13];
  const float* ln_g   = (const float*)d_in[14];
  const float* ln_b   = (const float*)d_in[15];
  const float* in_W   = (const float*)d_in[16];
  const float* conv_W = (const float*)d_in[17];
  const float* conv_b = (const float*)d_in[18];
  const float* xp_W   = (const float*)d_in[19];
  const float* dt_W   = (const float*)d_in[20];
  const float* dt_b   = (const float*)d_in[21];
  const float* A_log  = (const float*)d_in[22];
  const float* D_p    = (const float*)d_in[23];
  const float* out_W  = (const float*)d_in[24];
  const float* nf_g   = (const float*)d_in[25];
  const float* nf_b   = (const float*)d_in[26];
  const float* dec_W0 = (const float*)d_in[27];
  const float* dec_b0 = (const float*)d_in[28];
  const float* dec_g0 = (const float*)d_in[29];
  const float* dec_be0= (const float*)d_in[30];
  const float* dec_W1 = (const float*)d_in[31];
  const float* dec_b1 = (const float*)d_in[32];
  const float* dec_g1 = (const float*)d_in[33];
  const float* dec_be1= (const float*)d_in[34];
  const float* dec_W2 = (const float*)d_in[35];
  const float* dec_b2 = (const float*)d_in[36];

  float* out = (float*)d_out;

  float* ws  = (float*)d_ws;
  float* S    = ws;                  // 1,048,576  (B,L,128)
  float* U    = S    + 1048576;      // 1,048,576; bf16 U lives here (Ub)
  float* XI   = U    + 1048576;      // 2,097,152  xi dense (B,L,256)
  float* Z    = XI   + 2097152;      // 2,097,152  z  dense (B,L,256)
  float* CBUF = Z    + 2097152;      // 2,097,152  xc f32 (B,L,256)
  float* GA   = CBUF + 2097152;      // 1,048,576
  float* GB   = GA   + 1048576;      // 1,048,576
  float* DBL  = GB   + 1048576;      //   327,680
  float* WBIN = DBL  + 327680;       //   196,608 slots: in_W bf16
  float* WBOUT= WBIN + 196608;       //    98,304 slots: out_W bf16
  float* WT0  = WBOUT+ 98304;        //    24,576: dec_W0 transposed
  float* WT1  = WT0  + 24576;        //     6,144: dec_W1 transposed
  float* EB0 = XI;                   // enc/dec scratch (<=1M each)
  float* EB1 = XI + 1048576;
  float* H0  = CBUF;
  float* UT  = CBUF;
  float* GNP = DBL;
  ushort* Ub    = (ushort*)U;
  ushort* Yb    = (ushort*)GA;
  ushort* WbIn  = (ushort*)WBIN;
  ushort* WbOut = (ushort*)WBOUT;

  // weight conversion + decoder-weight transposes
  k_castb<<<1536, 256, 0, stream>>>(in_W,  WbIn,  NLAYER*512*DM);
  k_castb<<<768, 256, 0, stream>>>(out_W, WbOut, NLAYER*DM*DI);
  k_trw<<<96, 256, 0, stream>>>(dec_W0, WT0, 128, 64);
  k_trw<<<24, 256, 0, stream>>>(dec_W1, WT1, 64, 32);

  // ---------------- encoder ----------------
  k_maskmul<<<512, 256, 0, stream>>>(x, mask, H0, NB*2*TT);
  k_conv_lds<2,32,64,1><<<512, 256, 0, stream>>>(H0, enc_W0, enc_b0, EB0, 4096);
  k_gn_part<<<128, 256, 0, stream>>>(EB0, GNP);
  k_gn_apply<<<4096, 256, 0, stream>>>(EB0, enc_g0, enc_be0, 2048, GNP);
  k_conv_lds<32,64,32,2><<<1024, 256, 0, stream>>>(EB0, enc_W1, enc_b1, EB1, 2048);
  k_gn_part<<<128, 256, 0, stream>>>(EB1, GNP);
  k_gn_apply<<<4096, 256, 0, stream>>>(EB1, enc_g1, enc_be1, 1024, GNP);
  k_conv_lds<64,128,32,4><<<1024, 256, 0, stream>>>(EB1, enc_W2, enc_b2, EB0, 1024);
  k_gn_part<<<128, 256, 0, stream>>>(EB0, GNP);
  k_gn_apply<<<4096, 256, 0, stream>>>(EB0, enc_g2, enc_be2, 512, GNP);
  k_transpose2<<<4096, 256, 0, stream>>>(EB0, S);

  // ---------------- mamba layers ----------------
  const int rows = NB*LL; // 8192
  for (int i = 0; i < NLAYER; i++){
    k_ln2b<<<2048, 256, 0, stream>>>(S, ln_g + i*DM, ln_b + i*DM, Ub, rows);
    k_mfma_split<<<dim3(4, 64), 256, 0, stream>>>(Ub, WbIn + (size_t)i*512*DM, XI, Z, DM);
    k_cconv2<<<8192, 256, 0, stream>>>(XI, conv_W + (size_t)i*DI*4, conv_b + (size_t)i*DI, CBUF);
    k_gemm_xp<<<256, 256, 0, stream>>>(CBUF, xp_W + (size_t)i*40*DI, DBL);
    k_scan_sum<<<256, 256, 0, stream>>>(CBUF, DBL,
                                        dt_W + (size_t)i*DI*8, dt_b + (size_t)i*DI,
                                        A_log + (size_t)i*DI*16, GA, GB);
    k_scan_emit<<<256, 256, 0, stream>>>(CBUF, DBL, Z,
                                         dt_W + (size_t)i*DI*8, dt_b + (size_t)i*DI,
                                         A_log + (size_t)i*DI*16, D_p + (size_t)i*DI, GA, GB, Yb);
    k_mfma_acc2<<<256, 256, 0, stream>>>(Yb, WbOut + (size_t)i*DM*DI, S, DI);
  }

  // ---------------- decoder ----------------
  k_ln2<<<2048, 256, 0, stream>>>(S, nf_g, nf_b, U, rows);
  k_transposeB<<<4096, 256, 0, stream>>>(U, UT);   // (b,t,c) -> (b,c,t)
  k_deconv_lds<128,64,16,2><<<1024, 256, 0, stream>>>(UT, WT0, dec_b0, EB0, 512, 512);
  k_gn_part<<<128, 256, 0, stream>>>(EB0, GNP);
  k_gn_apply<<<4096, 256, 0, stream>>>(EB0, dec_g0, dec_be0, 1024, GNP);
  k_deconv_lds<64,32,32,2><<<1024, 256, 0, stream>>>(EB0, WT1, dec_b1, EB1, 1024, 1024);
  k_gn_part<<<128, 256, 0, stream>>>(EB1, GNP);
  k_gn_apply<<<4096, 256, 0, stream>>>(EB1, dec_g1, dec_be1, 2048, GNP);
  k_deconv2p<<<16*2*8, 256, 0, stream>>>(EB1, dec_W2, dec_b2, out, 32, 2, 2048, 2048, 8);

  // echoes (f32)
  k_copyf<<<512, 256, 0, stream>>>(x,    out + 131072, 131072);
  k_copyf<<<512, 256, 0, stream>>>(mask, out + 262144, 131072);
}

// Round 26
// 801.101 us; speedup vs baseline: 1.1506x; 1.1506x over previous
//
#include <hip/hip_runtime.h>
#include <hip/hip_bf16.h>
#include <math.h>

#define NB 16
#define TT 4096
#define LL 512
#define DM 128
#define DI 256
#define NLAYER 6
#define CL 32
#define NCH 16

typedef __bf16 bf16x8 __attribute__((ext_vector_type(8)));
typedef float f32x4 __attribute__((ext_vector_type(4)));
typedef unsigned short ushort;

static __device__ __forceinline__ float gelu_f(float v){
  return 0.5f*v*(1.f + erff(v*0.70710678118654752f));
}
static __device__ __forceinline__ float silu_f(float v){
  return v/(1.f + __expf(-v));
}
static __device__ __forceinline__ ushort f2b(float v){
  __hip_bfloat16 h = __float2bfloat16(v);
  return *(ushort*)&h;
}

__global__ __launch_bounds__(256) void k_maskmul(const float* __restrict__ x, const float* __restrict__ m,
                          float* __restrict__ out, int n){
  int i = blockIdx.x*256 + threadIdx.x;
  if (i < n) out[i] = x[i]*m[i];
}

__global__ __launch_bounds__(256) void k_castb(const float* __restrict__ in, ushort* __restrict__ out, int n){
  int i = blockIdx.x*256 + threadIdx.x;
  if (i < n) out[i] = f2b(in[i]);
}

// transpose weights (Ci,Co,3) -> (Co,Ci,3)
__global__ __launch_bounds__(256) void k_trw(const float* __restrict__ in, float* __restrict__ out, int Ci, int Co){
  int idx = blockIdx.x*256 + threadIdx.x;
  int n = Ci*Co*3;
  if (idx >= n) return;
  int k = idx % 3;
  int o = (idx/3) % Co;
  int ci = idx/(3*Co);
  out[((size_t)o*Ci + ci)*3 + k] = in[idx];
}

// LDS-staged conv1d stride2 pad1 k3. block=(b, L-chunk, Co-split). W (Co,Ci,3).
template<int Ci, int Co, int TW, int OS>
__global__ __launch_bounds__(256) void k_conv_lds(const float* __restrict__ x, const float* __restrict__ W,
                        const float* __restrict__ bias, float* __restrict__ y, int Li){
  const int Lc = TW;
  const int Lo = Li >> 1;
  const int S  = Lo / Lc;
  const int CoB = Co / OS;
  __shared__ float xe[Ci][Lc+1];
  __shared__ float xo[Ci][Lc+1];
  int bid = blockIdx.x;
  int os = bid % OS;
  int ch = (bid / OS) % S;
  int b  = bid / (OS*S);
  int t0 = ch*Lc;
  const float* xb = x + (size_t)b*Ci*Li;
  for (int idx = threadIdx.x; idx < Ci*(2*Lc+1); idx += 256){
    int ci = idx / (2*Lc+1);
    int j  = idx - ci*(2*Lc+1);
    int gin = 2*t0 - 1 + j;
    float v = (gin >= 0 && gin < Li) ? xb[(size_t)ci*Li + gin] : 0.f;
    if (j & 1) xo[ci][j>>1] = v;
    else       xe[ci][j>>1] = v;
  }
  __syncthreads();
  const int NOg = 256/TW;
  const int OI  = CoB/NOg;
  int tl = threadIdx.x % TW;
  int og = threadIdx.x / TW;
  #pragma unroll
  for (int oi = 0; oi < OI; oi++){
    int o = os*CoB + oi*NOg + og;
    const float* w = W + (size_t)o*Ci*3;
    float acc = bias[o];
    #pragma unroll 4
    for (int ci = 0; ci < Ci; ci++){
      float w0 = w[ci*3+0], w1 = w[ci*3+1], w2 = w[ci*3+2];
      acc += w0*xe[ci][tl] + w1*xo[ci][tl] + w2*xe[ci][tl+1];
    }
    y[((size_t)b*Co + o)*Lo + t0 + tl] = acc;
  }
}

// -------- GroupNorm(1): wide 2-kernel version --------
__global__ __launch_bounds__(256) void k_gn_part(const float* __restrict__ x, float* __restrict__ gp){
  int b = blockIdx.x >> 3, k8 = blockIdx.x & 7;
  const float* xb = x + (size_t)b*65536 + (size_t)k8*8192;
  float s = 0.f, s2 = 0.f;
  for (int i = threadIdx.x; i < 8192; i += 256){ float v = xb[i]; s += v; s2 += v*v; }
  #pragma unroll
  for (int o = 32; o; o >>= 1){ s += __shfl_down(s, o); s2 += __shfl_down(s2, o); }
  __shared__ float sh[8];
  int wid = threadIdx.x >> 6;
  if ((threadIdx.x & 63) == 0){ sh[wid] = s; sh[wid+4] = s2; }
  __syncthreads();
  if (threadIdx.x == 0){
    float a = sh[0]+sh[1]+sh[2]+sh[3], a2 = sh[4]+sh[5]+sh[6]+sh[7];
    gp[(b*8+k8)*2+0] = a; gp[(b*8+k8)*2+1] = a2;
  }
}
__global__ __launch_bounds__(256) void k_gn_apply(float* __restrict__ x, const float* __restrict__ g,
                          const float* __restrict__ be, int Tl, const float* __restrict__ gp){
  int gidx = blockIdx.x*256 + threadIdx.x;
  int b = gidx >> 16, i = gidx & 65535;
  float s = 0.f, s2 = 0.f;
  #pragma unroll
  for (int k = 0; k < 8; k++){ s += gp[(b*8+k)*2]; s2 += gp[(b*8+k)*2+1]; }
  float mean = s*(1.f/65536.f);
  float inv  = rsqrtf(s2*(1.f/65536.f) - mean*mean + 1e-5f);
  int c = i / Tl;
  float* p = x + (size_t)b*65536 + i;
  float v = (*p - mean)*inv*g[c] + be[c];
  *p = gelu_f(v);
}

// (B,128,512) NCH -> (B,512,128) BLD.
__global__ __launch_bounds__(256) void k_transpose2(const float* __restrict__ in, float* __restrict__ out){
  int idx = blockIdx.x*256 + threadIdx.x;
  if (idx >= NB*DM*LL) return;
  int t = idx & 511;
  int c = (idx >> 9) & 127;
  int b = idx >> 16;
  out[(size_t)b*65536 + (size_t)t*128 + c] = in[idx];
}

// (B,512,128) BLD -> (B,128,512) NCH.
__global__ __launch_bounds__(256) void k_transposeB(const float* __restrict__ in, float* __restrict__ out){
  int idx = blockIdx.x*256 + threadIdx.x;
  if (idx >= NB*DM*LL) return;
  int m = idx & 511;
  int c = (idx >> 9) & 127;
  int b = idx >> 16;
  out[idx] = in[(size_t)b*65536 + (size_t)m*128 + c];
}

// LayerNorm last-dim(128) -> f32 out.
__global__ __launch_bounds__(256) void k_ln2(const float* __restrict__ x, const float* __restrict__ g,
                      const float* __restrict__ be, float* __restrict__ out, int rows){
  int row = blockIdx.x*4 + (threadIdx.x >> 6);
  if (row >= rows) return;
  int lid = threadIdx.x & 63;
  const float* xr = x + (size_t)row*DM;
  float v0 = xr[lid], v1 = xr[lid+64];
  float s = v0 + v1;
  #pragma unroll
  for (int o = 32; o; o >>= 1) s += __shfl_xor(s, o);
  float mean = s*(1.f/128.f);
  float d0 = v0-mean, d1 = v1-mean;
  float s2 = d0*d0 + d1*d1;
  #pragma unroll
  for (int o = 32; o; o >>= 1) s2 += __shfl_xor(s2, o);
  float inv = rsqrtf(s2*(1.f/128.f) + 1e-5f);
  float* orow = out + (size_t)row*DM;
  orow[lid]    = d0*inv*g[lid]    + be[lid];
  orow[lid+64] = d1*inv*g[lid+64] + be[lid+64];
}

// LayerNorm -> bf16 out.
__global__ __launch_bounds__(256) void k_ln2b(const float* __restrict__ x, const float* __restrict__ g,
                      const float* __restrict__ be, ushort* __restrict__ out, int rows){
  int row = blockIdx.x*4 + (threadIdx.x >> 6);
  if (row >= rows) return;
  int lid = threadIdx.x & 63;
  const float* xr = x + (size_t)row*DM;
  float v0 = xr[lid], v1 = xr[lid+64];
  float s = v0 + v1;
  #pragma unroll
  for (int o = 32; o; o >>= 1) s += __shfl_xor(s, o);
  float mean = s*(1.f/128.f);
  float d0 = v0-mean, d1 = v1-mean;
  float s2 = d0*d0 + d1*d1;
  #pragma unroll
  for (int o = 32; o; o >>= 1) s2 += __shfl_xor(s2, o);
  float inv = rsqrtf(s2*(1.f/128.f) + 1e-5f);
  ushort* orow = out + (size_t)row*DM;
  orow[lid]    = f2b(d0*inv*g[lid]    + be[lid]);
  orow[lid+64] = f2b(d1*inv*g[lid+64] + be[lid+64]);
}

// bf16 MFMA GEMM with SPLIT epilogue: cols<256 -> C0 (xi), cols>=256 -> C1 (z).
__global__ __launch_bounds__(256) void k_mfma_split(const ushort* __restrict__ A, const ushort* __restrict__ B,
                          float* __restrict__ C0, float* __restrict__ C1, int K){
  int tid = threadIdx.x;
  int wid = tid >> 6, l = tid & 63;
  int wm = wid >> 1, wn = wid & 1;
  int m0 = blockIdx.y*128 + wm*64;
  int n0 = blockIdx.x*128 + wn*64;
  int lr = l & 15;
  int lk = (l >> 4)*8;
  int orow = (l >> 4)*4;
  f32x4 acc[4][4];
  #pragma unroll
  for (int i = 0; i < 4; i++)
    #pragma unroll
    for (int j = 0; j < 4; j++) acc[i][j] = (f32x4){0.f,0.f,0.f,0.f};
  for (int k0 = 0; k0 < K; k0 += 32){
    bf16x8 a[4], b[4];
    #pragma unroll
    for (int f = 0; f < 4; f++)
      a[f] = *(const bf16x8*)(A + (size_t)(m0 + f*16 + lr)*K + k0 + lk);
    #pragma unroll
    for (int f = 0; f < 4; f++)
      b[f] = *(const bf16x8*)(B + (size_t)(n0 + f*16 + lr)*K + k0 + lk);
    #pragma unroll
    for (int i = 0; i < 4; i++)
      #pragma unroll
      for (int j = 0; j < 4; j++)
        acc[i][j] = __builtin_amdgcn_mfma_f32_16x16x32_bf16(a[i], b[j], acc[i][j], 0, 0, 0);
  }
  float* C    = (n0 < 256) ? C0 : C1;
  int ncol0   = (n0 < 256) ? n0 : n0 - 256;
  #pragma unroll
  for (int i = 0; i < 4; i++)
    #pragma unroll
    for (int j = 0; j < 4; j++)
      #pragma unroll
      for (int r = 0; r < 4; r++)
        C[(size_t)(m0 + i*16 + orow + r)*256 + ncol0 + j*16 + lr] = acc[i][j][r];
}

// bf16 MFMA out-proj (accumulate), 32x128 block tile, wave = 32x32. grid = M/32 = 256 blocks.
__global__ __launch_bounds__(256) void k_mfma_acc2(const ushort* __restrict__ A, const ushort* __restrict__ B,
                          float* __restrict__ C, int K){
  int tid = threadIdx.x;
  int wid = tid >> 6, l = tid & 63;
  int m0 = blockIdx.x*32;
  int n0 = wid*32;
  int lr = l & 15;
  int lk = (l >> 4)*8;
  int orow = (l >> 4)*4;
  f32x4 acc[2][2];
  #pragma unroll
  for (int i = 0; i < 2; i++)
    #pragma unroll
    for (int j = 0; j < 2; j++)
      #pragma unroll
      for (int r = 0; r < 4; r++)
        acc[i][j][r] = C[(size_t)(m0 + i*16 + orow + r)*128 + n0 + j*16 + lr];
  for (int k0 = 0; k0 < K; k0 += 32){
    bf16x8 a[2], b[2];
    #pragma unroll
    for (int f = 0; f < 2; f++)
      a[f] = *(const bf16x8*)(A + (size_t)(m0 + f*16 + lr)*K + k0 + lk);
    #pragma unroll
    for (int f = 0; f < 2; f++)
      b[f] = *(const bf16x8*)(B + (size_t)(n0 + f*16 + lr)*K + k0 + lk);
    #pragma unroll
    for (int i = 0; i < 2; i++)
      #pragma unroll
      for (int j = 0; j < 2; j++)
        acc[i][j] = __builtin_amdgcn_mfma_f32_16x16x32_bf16(a[i], b[j], acc[i][j], 0, 0, 0);
  }
  #pragma unroll
  for (int i = 0; i < 2; i++)
    #pragma unroll
    for (int j = 0; j < 2; j++)
      #pragma unroll
      for (int r = 0; r < 4; r++)
        C[(size_t)(m0 + i*16 + orow + r)*128 + n0 + j*16 + lr] = acc[i][j][r];
}

// xp-proj GEMM f32: 32x64 tile (N=40 guarded).
__global__ __launch_bounds__(256) void k_gemm_xp(const float* __restrict__ A, const float* __restrict__ B,
                          float* __restrict__ C){
  __shared__ float As[32][17];
  __shared__ float Bs[64][17];
  int tid = threadIdx.x;
  int m0 = blockIdx.x*32;
  int tx = tid & 15, ty = tid >> 4;
  float acc[2][4] = {};
  for (int k0 = 0; k0 < 256; k0 += 16){
    if (tid < 128){
      int r = tid >> 2, c = (tid & 3)*4;
      float4 av = *(const float4*)(A + (size_t)(m0+r)*256 + k0 + c);
      As[r][c]=av.x; As[r][c+1]=av.y; As[r][c+2]=av.z; As[r][c+3]=av.w;
    }
    {
      int r = tid >> 2, c = (tid & 3)*4;
      float4 bv = make_float4(0.f,0.f,0.f,0.f);
      if (r < 40) bv = *(const float4*)(B + (size_t)r*256 + k0 + c);
      Bs[r][c]=bv.x; Bs[r][c+1]=bv.y; Bs[r][c+2]=bv.z; Bs[r][c+3]=bv.w;
    }
    __syncthreads();
    #pragma unroll
    for (int k = 0; k < 16; k++){
      float a[2], bb[4];
      #pragma unroll
      for (int i = 0; i < 2; i++) a[i] = As[ty*2+i][k];
      #pragma unroll
      for (int j = 0; j < 4; j++) bb[j] = Bs[tx*4+j][k];
      #pragma unroll
      for (int i = 0; i < 2; i++)
        #pragma unroll
        for (int j = 0; j < 4; j++) acc[i][j] += a[i]*bb[j];
    }
    __syncthreads();
  }
  #pragma unroll
  for (int i = 0; i < 2; i++){
    int m = m0 + ty*2 + i;
    #pragma unroll
    for (int j = 0; j < 4; j++){
      int n = tx*4 + j;
      if (n < 40) C[(size_t)m*40 + n] = acc[i][j];
    }
  }
}

// depthwise causal conv k=4 over dense XI (B,L,256), +bias, SiLU -> XC (B,L,256)
__global__ __launch_bounds__(256) void k_cconv2(const float* __restrict__ xi, const float* __restrict__ cw,
                         const float* __restrict__ cb, float* __restrict__ xc){
  int idx = blockIdx.x*256 + threadIdx.x;
  if (idx >= NB*LL*DI) return;
  int d = idx & 255;
  int l = (idx >> 8) & 511;
  int b = idx >> 17;
  const float* xp = xi + (size_t)b*131072 + d;
  float acc = cb[d];
  #pragma unroll
  for (int j = 0; j < 4; j++){
    int m = l - 3 + j;
    if (m >= 0) acc += xp[(size_t)m*256]*cw[d*4 + j];
  }
  xc[idx] = silu_f(acc);
}

// ---------------- chunked scan, thread = d ----------------
__global__ __launch_bounds__(256) void k_scan_sum(const float* __restrict__ xc, const float* __restrict__ dbl,
                        const float* __restrict__ dtW, const float* __restrict__ dtb,
                        const float* __restrict__ Alog,
                        float* __restrict__ GA, float* __restrict__ GB){
  __shared__ float srow[CL*40];
  int bid = blockIdx.x;
  int b = bid >> 4, ch = bid & 15;
  int d = threadIdx.x;
  const float* dbp = dbl + (size_t)b*20480 + ch*CL*40;
  for (int j = d; j < CL*40; j += 256) srow[j] = dbp[j];
  float4 w0 = *(const float4*)(dtW + d*8);
  float4 w1 = *(const float4*)(dtW + d*8 + 4);
  float tb = dtb[d];
  float a[16];
  #pragma unroll
  for (int s = 0; s < 16; s++) a[s] = -__expf(Alog[d*16 + s]);
  const float* xcp = xc + (size_t)b*131072 + (size_t)ch*CL*256 + d;
  __syncthreads();
  float A[16], Bv[16];
  #pragma unroll
  for (int s = 0; s < 16; s++){ A[s] = 1.f; Bv[s] = 0.f; }
  #pragma unroll 2
  for (int i = 0; i < CL; i++){
    const float* r = srow + i*40;
    float raw = tb + r[0]*w0.x + r[1]*w0.y + r[2]*w0.z + r[3]*w0.w
                   + r[4]*w1.x + r[5]*w1.y + r[6]*w1.z + r[7]*w1.w;
    float dt = (raw > 20.f) ? raw : log1pf(__expf(raw));
    float xcv = xcp[(size_t)i*256];
    float dxc = dt*xcv;
    #pragma unroll
    for (int s = 0; s < 16; s++){
      float e = __expf(dt*a[s]);
      A[s] *= e;
      Bv[s] = e*Bv[s] + dxc*r[8+s];
    }
  }
  size_t base = (((size_t)b*NCH + ch)*16)*256 + d;
  #pragma unroll
  for (int s = 0; s < 16; s++){
    GA[base + (size_t)s*256] = A[s];
    GB[base + (size_t)s*256] = Bv[s];
  }
}

__global__ __launch_bounds__(256) void k_scan_pre(const float* __restrict__ GA, float* __restrict__ GB){
  int gid = blockIdx.x*256 + threadIdx.x;
  int b = gid >> 12;
  int s = (gid >> 8) & 15;
  int d = gid & 255;
  size_t stride = (size_t)16*256;
  size_t idx = (((size_t)b*NCH)*16 + s)*256 + d;
  float P = 0.f;
  #pragma unroll
  for (int ch = 0; ch < NCH; ch++){
    float Ac = GA[idx], Bc = GB[idx];
    GB[idx] = P;
    P = Ac*P + Bc;
    idx += stride;
  }
}

__global__ __launch_bounds__(256) void k_scan_emit(const float* __restrict__ xc, const float* __restrict__ dbl,
                        const float* __restrict__ z,
                        const float* __restrict__ dtW, const float* __restrict__ dtb,
                        const float* __restrict__ Alog, const float* __restrict__ Dp,
                        const float* __restrict__ GB, ushort* __restrict__ yb){
  __shared__ float srow[CL*40];
  int bid = blockIdx.x;
  int b = bid >> 4, ch = bid & 15;
  int d = threadIdx.x;
  const float* dbp = dbl + (size_t)b*20480 + ch*CL*40;
  for (int j = d; j < CL*40; j += 256) srow[j] = dbp[j];
  float4 w0 = *(const float4*)(dtW + d*8);
  float4 w1 = *(const float4*)(dtW + d*8 + 4);
  float tb = dtb[d];
  float Dd = Dp[d];
  float a[16];
  #pragma unroll
  for (int s = 0; s < 16; s++) a[s] = -__expf(Alog[d*16 + s]);
  float h[16];
  size_t base = (((size_t)b*NCH + ch)*16)*256 + d;
  #pragma unroll
  for (int s = 0; s < 16; s++) h[s] = GB[base + (size_t)s*256];
  const float* xcp = xc + (size_t)b*131072 + (size_t)ch*CL*256 + d;
  const float* zp  = z  + (size_t)b*131072 + (size_t)ch*CL*256 + d;
  ushort* yp = yb + (size_t)b*131072 + (size_t)ch*CL*256 + d;
  __syncthreads();
  #pragma unroll 2
  for (int i = 0; i < CL; i++){
    const float* r = srow + i*40;
    float raw = tb + r[0]*w0.x + r[1]*w0.y + r[2]*w0.z + r[3]*w0.w
                   + r[4]*w1.x + r[5]*w1.y + r[6]*w1.z + r[7]*w1.w;
    float dt = (raw > 20.f) ? raw : log1pf(__expf(raw));
    float xcv = xcp[(size_t)i*256];
    float dxc = dt*xcv;
    float y = Dd*xcv;
    #pragma unroll
    for (int s = 0; s < 16; s++){
      float e = __expf(dt*a[s]);
      h[s] = e*h[s] + dxc*r[8+s];
      y += h[s]*r[24+s];
    }
    float zv = zp[(size_t)i*256];
    yp[(size_t)i*256] = f2b(y*silu_f(zv));
  }
}

// LDS-staged paired deconv, transposed weights (Co,Ci,3), Co-split OS.
template<int Ci, int Co, int TW, int OS>
__global__ __launch_bounds__(256) void k_deconv_lds(const float* __restrict__ x, const float* __restrict__ WT,
                          const float* __restrict__ bias, float* __restrict__ y, int Li, int cs){
  const int Lc = TW;
  const int S  = Li / Lc;
  const int CoB = Co / OS;
  __shared__ float xin[Ci][Lc+1];
  int bid = blockIdx.x;
  int os = bid % OS;
  int ch = (bid / OS) % S;
  int b  = bid / (OS*S);
  int m0 = ch*Lc;
  const float* xb = x + (size_t)b*Ci*Li;
  for (int idx = threadIdx.x; idx < Ci*(Lc+1); idx += 256){
    int ci = idx / (Lc+1);
    int q  = idx - ci*(Lc+1);
    int m  = m0 + q;
    xin[ci][q] = (m < Li) ? xb[(size_t)ci*cs + m] : 0.f;
  }
  __syncthreads();
  const int NOg = 256/TW;
  const int OI  = CoB/NOg;
  int tl = threadIdx.x % TW;
  int og = threadIdx.x / TW;
  float* yo = y + (size_t)b*Co*(size_t)(2*Li);
  #pragma unroll
  for (int oi = 0; oi < OI; oi++){
    int o = os*CoB + oi*NOg + og;
    const float* w = WT + (size_t)o*Ci*3;
    float bo = bias[o];
    float even = bo, odd = bo;
    #pragma unroll 4
    for (int ci = 0; ci < Ci; ci++){
      float w0 = w[ci*3+0], w1 = w[ci*3+1], w2 = w[ci*3+2];
      float xm  = xin[ci][tl];
      float xm1 = xin[ci][tl+1];
      even += w1*xm;
      odd  += w2*xm + w0*xm1;
    }
    *(float2*)(yo + (size_t)o*(2*Li) + 2*(m0 + tl)) = make_float2(even, odd);
  }
}

// paired deconv (non-LDS) for dec2 (Co=2).
__global__ __launch_bounds__(256) void k_deconv2p(const float* __restrict__ x, const float* __restrict__ W,
                          const float* __restrict__ bias, float* __restrict__ y,
                          int Ci, int Co, int Li, int cs, int S){
  __shared__ float w[384];
  int bid = blockIdx.x;
  int ch = bid % S;
  int o  = (bid / S) % Co;
  int b  = bid / (S*Co);
  for (int j = threadIdx.x; j < Ci*3; j += 256){
    int i = j/3, k = j - 3*i;
    w[j] = W[((size_t)i*Co + o)*3 + k];
  }
  __syncthreads();
  int Lc = Li / S;
  int m0 = ch*Lc;
  const float* xb = x + (size_t)b*Ci*Li;
  float bo = bias[o];
  float* yo = y + ((size_t)b*Co + o)*(size_t)(2*Li);
  for (int idx = threadIdx.x; idx < Lc; idx += 256){
    int m = m0 + idx;
    float even = bo, odd = bo;
    bool has1 = (m + 1 < Li);
    for (int i = 0; i < Ci; i++){
      const float* xr = xb + (size_t)i*cs;
      float xm  = xr[m];
      float xm1 = has1 ? xr[m+1] : 0.f;
      even += w[i*3+1]*xm;
      odd  += w[i*3+2]*xm + w[i*3+0]*xm1;
    }
    *(float2*)(yo + 2*m) = make_float2(even, odd);
  }
}

__global__ __launch_bounds__(256) void k_copyf(const float* __restrict__ in, float* __restrict__ out, int n){
  int i = blockIdx.x*256 + threadIdx.x;
  if (i < n) out[i] = in[i];
}

extern "C" void kernel_launch(void* const* d_in, const int* in_sizes, int n_in,
                              void* d_out, int out_size, void* d_ws, size_t ws_size,
                              hipStream_t stream) {
  const float* x      = (const float*)d_in[0];
  const float* mask   = (const float*)d_in[1];
  const float* enc_W0 = (const float*)d_in[2];
  const float* enc_b0 = (const float*)d_in[3];
  const float* enc_g0 = (const float*)d_in[4];
  const float* enc_be0= (const float*)d_in[5];
  const float* enc_W1 = (const float*)d_in[6];
  const float* enc_b1 = (const float*)d_in[7];
  const float* enc_g1 = (const float*)d_in[8];
  const float* enc_be1= (const float*)d_in[9];
  const float* enc_W2 = (const float*)d_in[10];
  const float* enc_b2 = (const float*)d_in[11];
  const float* enc_g2 = (const float*)d_in[12];
  const float* enc_be2= (const float*)d_in[13];
  const float* ln_g   = (const float*)d_in[14];
  const float* ln_b   = (const float*)d_in[15];
  const float* in_W   = (const float*)d_in[16];
  const float* conv_W = (const float*)d_in[17];
  const float* conv_b = (const float*)d_in[18];
  const float* xp_W   = (const float*)d_in[19];
  const float* dt_W   = (const float*)d_in[20];
  const float* dt_b   = (const float*)d_in[21];
  const float* A_log  = (const float*)d_in[22];
  const float* D_p    = (const float*)d_in[23];
  const float* out_W  = (const float*)d_in[24];
  const float* nf_g   = (const float*)d_in[25];
  const float* nf_b   = (const float*)d_in[26];
  const float* dec_W0 = (const float*)d_in[27];
  const float* dec_b0 = (const float*)d_in[28];
  const float* dec_g0 = (const float*)d_in[29];
  const float* dec_be0= (const float*)d_in[30];
  const float* dec_W1 = (const float*)d_in[31];
  const float* dec_b1 = (const float*)d_in[32];
  const float* dec_g1 = (const float*)d_in[33];
  const float* dec_be1= (const float*)d_in[34];
  const float* dec_W2 = (const float*)d_in[35];
  const float* dec_b2 = (const float*)d_in[36];

  float* out = (float*)d_out;

  float* ws  = (float*)d_ws;
  float* S    = ws;                  // 1,048,576  (B,L,128)
  float* U    = S    + 1048576;      // 1,048,576; bf16 U lives here (Ub)
  float* XI   = U    + 1048576;      // 2,097,152  xi dense (B,L,256)
  float* Z    = XI   + 2097152;      // 2,097,152  z  dense (B,L,256)
  float* CBUF = Z    + 2097152;      // 2,097,152  xc f32 (B,L,256)
  float* GA   = CBUF + 2097152;      // 1,048,576
  float* GB   = GA   + 1048576;      // 1,048,576
  float* DBL  = GB   + 1048576;      //   327,680
  float* WBIN = DBL  + 327680;       //   196,608 slots: in_W bf16
  float* WBOUT= WBIN + 196608;       //    98,304 slots: out_W bf16
  float* WT0  = WBOUT+ 98304;        //    24,576: dec_W0 transposed
  float* WT1  = WT0  + 24576;        //     6,144: dec_W1 transposed
  float* EB0 = XI;                   // enc/dec scratch (<=1M each)
  float* EB1 = XI + 1048576;
  float* H0  = CBUF;
  float* UT  = CBUF;
  float* GNP = DBL;
  ushort* Ub    = (ushort*)U;
  ushort* Yb    = (ushort*)GA;
  ushort* WbIn  = (ushort*)WBIN;
  ushort* WbOut = (ushort*)WBOUT;

  // weight conversion + decoder-weight transposes
  k_castb<<<1536, 256, 0, stream>>>(in_W,  WbIn,  NLAYER*512*DM);
  k_castb<<<768, 256, 0, stream>>>(out_W, WbOut, NLAYER*DM*DI);
  k_trw<<<96, 256, 0, stream>>>(dec_W0, WT0, 128, 64);
  k_trw<<<24, 256, 0, stream>>>(dec_W1, WT1, 64, 32);

  // ---------------- encoder ----------------
  k_maskmul<<<512, 256, 0, stream>>>(x, mask, H0, NB*2*TT);
  k_conv_lds<2,32,64,1><<<512, 256, 0, stream>>>(H0, enc_W0, enc_b0, EB0, 4096);
  k_gn_part<<<128, 256, 0, stream>>>(EB0, GNP);
  k_gn_apply<<<4096, 256, 0, stream>>>(EB0, enc_g0, enc_be0, 2048, GNP);
  k_conv_lds<32,64,32,2><<<1024, 256, 0, stream>>>(EB0, enc_W1, enc_b1, EB1, 2048);
  k_gn_part<<<128, 256, 0, stream>>>(EB1, GNP);
  k_gn_apply<<<4096, 256, 0, stream>>>(EB1, enc_g1, enc_be1, 1024, GNP);
  k_conv_lds<64,128,32,4><<<1024, 256, 0, stream>>>(EB1, enc_W2, enc_b2, EB0, 1024);
  k_gn_part<<<128, 256, 0, stream>>>(EB0, GNP);
  k_gn_apply<<<4096, 256, 0, stream>>>(EB0, enc_g2, enc_be2, 512, GNP);
  k_transpose2<<<4096, 256, 0, stream>>>(EB0, S);

  // ---------------- mamba layers ----------------
  const int rows = NB*LL; // 8192
  for (int i = 0; i < NLAYER; i++){
    k_ln2b<<<2048, 256, 0, stream>>>(S, ln_g + i*DM, ln_b + i*DM, Ub, rows);
    k_mfma_split<<<dim3(4, 64), 256, 0, stream>>>(Ub, WbIn + (size_t)i*512*DM, XI, Z, DM);
    k_cconv2<<<8192, 256, 0, stream>>>(XI, conv_W + (size_t)i*DI*4, conv_b + (size_t)i*DI, CBUF);
    k_gemm_xp<<<256, 256, 0, stream>>>(CBUF, xp_W + (size_t)i*40*DI, DBL);
    k_scan_sum<<<256, 256, 0, stream>>>(CBUF, DBL,
                                        dt_W + (size_t)i*DI*8, dt_b + (size_t)i*DI,
                                        A_log + (size_t)i*DI*16, GA, GB);
    k_scan_pre<<<256, 256, 0, stream>>>(GA, GB);
    k_scan_emit<<<256, 256, 0, stream>>>(CBUF, DBL, Z,
                                         dt_W + (size_t)i*DI*8, dt_b + (size_t)i*DI,
                                         A_log + (size_t)i*DI*16, D_p + (size_t)i*DI, GB, Yb);
    k_mfma_acc2<<<256, 256, 0, stream>>>(Yb, WbOut + (size_t)i*DM*DI, S, DI);
  }

  // ---------------- decoder ----------------
  k_ln2<<<2048, 256, 0, stream>>>(S, nf_g, nf_b, U, rows);
  k_transposeB<<<4096, 256, 0, stream>>>(U, UT);   // (b,t,c) -> (b,c,t)
  k_deconv_lds<128,64,16,2><<<1024, 256, 0, stream>>>(UT, WT0, dec_b0, EB0, 512, 512);
  k_gn_part<<<128, 256, 0, stream>>>(EB0, GNP);
  k_gn_apply<<<4096, 256, 0, stream>>>(EB0, dec_g0, dec_be0, 1024, GNP);
  k_deconv_lds<64,32,32,2><<<1024, 256, 0, stream>>>(EB0, WT1, dec_b1, EB1, 1024, 1024);
  k_gn_part<<<128, 256, 0, stream>>>(EB1, GNP);
  k_gn_apply<<<4096, 256, 0, stream>>>(EB1, dec_g1, dec_be1, 2048, GNP);
  k_deconv2p<<<16*2*8, 256, 0, stream>>>(EB1, dec_W2, dec_b2, out, 32, 2, 2048, 2048, 8);

  // echoes (f32)
  k_copyf<<<512, 256, 0, stream>>>(x,    out + 131072, 131072);
  k_copyf<<<512, 256, 0, stream>>>(mask, out + 262144, 131072);
}